// Round 1
// baseline (1270.729 us; speedup 1.0000x reference)
//
#include <hip/hip_runtime.h>

// ---- problem constants ----
#define OUTW 222
#define PLANE (OUTW * OUTW)       // 49284 (divisible by 4)
#define INW 224
#define INPLANE (INW * INW)       // 50176
#define NGROUPS 3                 // M
#define OCPG 64                   // N*G channels per group
#define TOTAL_OC 192              // M*N*G
#define NBATCH 32

// cos/sin of linspace(-90,90,8) degrees: angle_g = -pi/2 + g*pi/7
// => cos = sin(g*pi/7), sin = -cos(g*pi/7)
__constant__ float ROT_C[8] = {
    0.0f, 0.43388373911755823f, 0.7818314824680298f, 0.9749279121818236f,
    0.9749279121818236f, 0.7818314824680298f, 0.43388373911755823f, 0.0f};
__constant__ float ROT_S[8] = {
    -1.0f, -0.9009688679024191f, -0.6234898018587336f, -0.22252093395631445f,
    0.22252093395631445f, 0.6234898018587336f, 0.9009688679024191f, 1.0f};

// Kernel 1: build the 192 rotated 3x3 filters (bilinear grid-sample of w).
// rotw layout: [o][tap], o = f*8 + g (f in [0,24), g in [0,8)), tap = dy*3+dx.
__global__ void rotw_kernel(const float* __restrict__ w, float* __restrict__ rotw) {
    int idx = blockIdx.x * blockDim.x + threadIdx.x;
    if (idx >= TOTAL_OC * 9) return;
    int o = idx / 9, t = idx - o * 9;
    int f = o >> 3, gr = o & 7;
    int h = t / 3, wv = t - h * 3;
    // coords = (2*i+1)/3 - 1
    float xx = (2.0f * (float)wv + 1.0f) / 3.0f - 1.0f;
    float yy = (2.0f * (float)h + 1.0f) / 3.0f - 1.0f;
    float c = ROT_C[gr], s = ROT_S[gr];
    float gx = c * xx - s * yy;
    float gy = s * xx + c * yy;
    float ix = ((gx + 1.0f) * 3.0f - 1.0f) * 0.5f;
    float iy = ((gy + 1.0f) * 3.0f - 1.0f) * 0.5f;
    float x0f = floorf(ix), y0f = floorf(iy);
    int x0 = (int)x0f, y0 = (int)y0f;
    float wx1 = ix - x0f, wy1 = iy - y0f;
    float wx0 = 1.0f - wx1, wy0 = 1.0f - wy1;
    const float* wf = w + f * 9;
    auto gat = [&](int xi, int yi) -> float {
        if (xi < 0 || xi > 2 || yi < 0 || yi > 2) return 0.0f;
        return wf[yi * 3 + xi];
    };
    rotw[idx] = gat(x0, y0) * (wx0 * wy0) + gat(x0 + 1, y0) * (wx1 * wy0) +
                gat(x0, y0 + 1) * (wx0 * wy1) + gat(x0 + 1, y0 + 1) * (wx1 * wy1);
}

// Kernel 2: grouped 3x3 VALID conv.
// Block: 256 threads, handles 1024 consecutive output pixels of one (n, ci)
// plane across all 64 output channels of the group. Each thread: 4 pixels,
// 3x3 neighborhoods kept in registers, float4 stores per channel.
__global__ __launch_bounds__(256) void rotconv_kernel(
    const float* __restrict__ x, const float* __restrict__ rotw,
    float* __restrict__ out) {
    __shared__ float4 sw4[OCPG * 3];  // 12 floats per channel (padded from 9)
    float* sw = (float*)sw4;

    const int tid = threadIdx.x;
    const int nc = blockIdx.y;      // n*3 + ci
    const int n = nc / 3;
    const int ci = nc - n * 3;

    // Stage this group's 64x9 weights into LDS (padded stride 12).
    for (int i = tid; i < OCPG * 9; i += 256) {
        int o = i / 9, t = i - o * 9;
        sw[o * 12 + t] = rotw[(ci * OCPG + o) * 9 + t];
    }
    __syncthreads();

    const int p0 = (blockIdx.x * 256 + tid) * 4;  // first of 4 pixels
    if (p0 >= PLANE) return;                      // tail threads (PLANE%4==0 => all-or-nothing)

    const float* inp = x + (size_t)nc * INPLANE;
    float v[4][9];
#pragma unroll
    for (int j = 0; j < 4; ++j) {
        int p = p0 + j;
        int y = p / OUTW;
        int xc = p - y * OUTW;
        const float* base = inp + y * INW + xc;
#pragma unroll
        for (int dy = 0; dy < 3; ++dy)
#pragma unroll
            for (int dx = 0; dx < 3; ++dx)
                v[j][dy * 3 + dx] = base[dy * INW + dx];
    }

    float* outp = out + (size_t)(n * TOTAL_OC + ci * OCPG) * PLANE + p0;
#pragma unroll 2
    for (int o = 0; o < OCPG; ++o) {
        const float4 wa = sw4[o * 3 + 0];  // w0..w3  (broadcast ds_read_b128)
        const float4 wb = sw4[o * 3 + 1];  // w4..w7
        const float w8 = sw4[o * 3 + 2].x; // w8
        float acc[4];
#pragma unroll
        for (int j = 0; j < 4; ++j) {
            float a;
            a = v[j][0] * wa.x;
            a = fmaf(v[j][1], wa.y, a);
            a = fmaf(v[j][2], wa.z, a);
            a = fmaf(v[j][3], wa.w, a);
            a = fmaf(v[j][4], wb.x, a);
            a = fmaf(v[j][5], wb.y, a);
            a = fmaf(v[j][6], wb.z, a);
            a = fmaf(v[j][7], wb.w, a);
            a = fmaf(v[j][8], w8, a);
            acc[j] = a;
        }
        *(float4*)outp = make_float4(acc[0], acc[1], acc[2], acc[3]);
        outp += PLANE;
    }
}

extern "C" void kernel_launch(void* const* d_in, const int* in_sizes, int n_in,
                              void* d_out, int out_size, void* d_ws, size_t ws_size,
                              hipStream_t stream) {
    const float* x = (const float*)d_in[0];    // (32,3,224,224) fp32
    const float* w = (const float*)d_in[1];    // (24,1,3,3) fp32
    float* out = (float*)d_out;                // (32,192,222,222) fp32
    float* rotw = (float*)d_ws;                // 192*9 floats scratch

    rotw_kernel<<<dim3(7), 256, 0, stream>>>(w, rotw);

    dim3 grid((PLANE / 4 + 255) / 256, NBATCH * NGROUPS);  // (49, 96)
    rotconv_kernel<<<grid, 256, 0, stream>>>(x, rotw, out);
}